// Round 4
// baseline (97.068 us; speedup 1.0000x reference)
//
#include <hip/hip_runtime.h>
#include <hip/hip_cooperative_groups.h>
#include <math.h>

namespace cg = cooperative_groups;

// Problem constants: N=12000, NEI=32, K=8, D=64
#define NPTS 12000
#define NNEI 32
#define KK   8
#define DD   64
#define PTSB 48                 // points per block (3 MFMA rounds of 16)
#define NBLK (NPTS / PTSB)      // 250 blocks -> 1 block/CU, co-resident for grid.sync
#define RNDS 3

typedef __bf16 bf16x8 __attribute__((ext_vector_type(8)));
typedef float  f32x4  __attribute__((ext_vector_type(4)));

#define MFMA16(A, B, C) __builtin_amdgcn_mfma_f32_16x16x32_bf16((A), (B), (C), 0, 0, 0)

__device__ __forceinline__ void pack8(float4 u, float4 v, bf16x8& h, bf16x8& l) {
    float a[8] = {u.x, u.y, u.z, u.w, v.x, v.y, v.z, v.w};
    #pragma unroll
    for (int i = 0; i < 8; ++i) {
        __bf16 hh = (__bf16)a[i];
        h[i] = hh;
        l[i] = (__bf16)(a[i] - (float)hh);
    }
}

// ================= fused cooperative kernel =================
// Phase P (prep): each wave k computes km[k] row into LDS, es = exp(scales[k]).
// Phase A (x3 rounds of 16 points): split-bf16 MFMA Y = X W^T (+ inner-product
//   tile for dis), epilogue stats, cross-k combine via LDS, F row store.
// grid.sync() (+threadfence for cross-XCD F visibility), then
// Phase B: same block aggregates its 48 n's: masked gather-sum of F rows,
//   lorentz normalize, store out.
__launch_bounds__(512, 2)
__global__ void fused_kernel(const float* __restrict__ x,
                             const int*  __restrict__ nei,
                             const int*  __restrict__ mask,
                             const float* __restrict__ kp,
                             const float* __restrict__ W,
                             const float* __restrict__ b,
                             const float* __restrict__ scales,
                             float* __restrict__ F,
                             float* __restrict__ out) {
    __shared__ float xtr[KK][16][65];   // pad 65 -> conflict-free combine reads
    __shared__ float kmL[KK][DD];
    __shared__ float disl[16][12];

    const int t    = threadIdx.x;
    const int k    = t >> 6;            // wave index == kernel index
    const int lane = t & 63;
    const int c    = lane & 15;
    const int g    = lane >> 4;

    // ---- prep (per block, redundant but ~free) ----
    {
        float spv = (lane == 0) ? 0.f : kp[k * DD + lane];   // kp[:,0]==0
        float ss = spv * spv;
        #pragma unroll
        for (int off = 32; off > 0; off >>= 1) ss += __shfl_xor(ss, off);
        float nrm = sqrtf(fmaxf(ss, 1e-8f));
        float e  = __expf(nrm);
        float ei = 1.0f / e;
        float ch = 0.5f * (e + ei);
        float sh = 0.5f * (e - ei);
        kmL[k][lane] = (lane == 0) ? ch : -(sh / nrm) * spv; // (kernels*metric)
    }
    const float es = __expf(scales[k]);

    // ---- W_k fragments (hi/lo), loaded once per block ----
    bf16x8 Wh[4][2], Wl[4][2];
    #pragma unroll
    for (int nt = 0; nt < 4; ++nt)
        #pragma unroll
        for (int ks = 0; ks < 2; ++ks) {
            const float* wr = W + ((size_t)k * DD + nt * 16 + c) * DD + ks * 32 + g * 8;
            pack8(*(const float4*)wr, *(const float4*)(wr + 4), Wh[nt][ks], Wl[nt][ks]);
        }
    float bnt[4];
    #pragma unroll
    for (int nt = 0; nt < 4; ++nt) bnt[nt] = b[k * DD + nt * 16 + c];

    __syncthreads();  // kmL ready

    // km fragments (rows 8..15 zero)
    bf16x8 Mh[2], Ml[2];
    #pragma unroll
    for (int ks = 0; ks < 2; ++ks)
        #pragma unroll
        for (int j = 0; j < 8; ++j) {
            float v = (c < 8) ? kmL[c][ks * 32 + g * 8 + j] : 0.f;
            __bf16 hh = (__bf16)v;
            Mh[ks][j] = hh;
            Ml[ks][j] = (__bf16)(v - (float)hh);
        }

    const int blk = blockIdx.x;

    for (int r = 0; r < RNDS; ++r) {
        const int pbase = blk * PTSB + r * 16;

        // A fragments for this round's 16 x-rows
        bf16x8 Ah[2], Al[2];
        {
            const float* xr = x + (size_t)(pbase + c) * DD + g * 8;
            pack8(*(const float4*)(xr +  0), *(const float4*)(xr +  4), Ah[0], Al[0]);
            pack8(*(const float4*)(xr + 32), *(const float4*)(xr + 36), Ah[1], Al[1]);
        }

        f32x4 accY[4];
        #pragma unroll
        for (int nt = 0; nt < 4; ++nt) accY[nt] = (f32x4){0.f, 0.f, 0.f, 0.f};
        f32x4 accI = (f32x4){0.f, 0.f, 0.f, 0.f};
        #pragma unroll
        for (int ks = 0; ks < 2; ++ks) {
            #pragma unroll
            for (int nt = 0; nt < 4; ++nt) {
                accY[nt] = MFMA16(Ah[ks], Wh[nt][ks], accY[nt]);
                accY[nt] = MFMA16(Ah[ks], Wl[nt][ks], accY[nt]);
                accY[nt] = MFMA16(Al[ks], Wh[nt][ks], accY[nt]);
            }
            accI = MFMA16(Ah[ks], Mh[ks], accI);
            accI = MFMA16(Ah[ks], Ml[ks], accI);
            accI = MFMA16(Al[ks], Mh[ks], accI);
        }

        // ---- epilogue: per-point stats (C layout: row p=g*4+rr, col o=nt*16+c) ----
        float yv[4][4], sall[4];
        #pragma unroll
        for (int rr = 0; rr < 4; ++rr) {
            float s = 0.f;
            #pragma unroll
            for (int nt = 0; nt < 4; ++nt) {
                float y = accY[nt][rr] + bnt[nt];
                yv[nt][rr] = y;
                s += y * y;
            }
            sall[rr] = s;
        }
        #pragma unroll
        for (int m = 1; m <= 8; m <<= 1)
            #pragma unroll
            for (int rr = 0; rr < 4; ++rr) sall[rr] += __shfl_xor(sall[rr], m);
        float y0[4];
        #pragma unroll
        for (int rr = 0; rr < 4; ++rr) y0[rr] = __shfl(yv[0][rr], lane & 48);

        #pragma unroll
        for (int rr = 0; rr < 4; ++rr) {
            const int p = g * 4 + rr;
            float nar2 = fmaxf(sall[rr] - y0[rr] * y0[rr], 1e-8f);
            float time = es / (1.0f + __expf(-y0[rr])) + 1.0001f;
            float s3   = sqrtf((time * time - 1.0f) / nar2);
            #pragma unroll
            for (int nt = 0; nt < 4; ++nt) {
                float v = yv[nt][rr] * s3;
                if (nt == 0 && c == 0) v = time;
                xtr[k][p][nt * 16 + c] = v;
            }
        }
        if (k == 0) {
            #pragma unroll
            for (int rr = 0; rr < 4; ++rr) {
                float nc  = fmaxf(accI[rr], 1.0f + 1e-7f);
                float dis = __logf(nc + sqrtf(nc * nc - 1.0f));  // arccosh
                if (c < 8) disl[g * 4 + rr][c] = dis;
            }
        }
        __syncthreads();

        // ---- combine: wave k handles points {2k, 2k+1} ----
        #pragma unroll
        for (int pi = 0; pi < 2; ++pi) {
            const int p = k * 2 + pi;
            float dk[KK];
            #pragma unroll
            for (int q = 0; q < KK; ++q) dk[q] = disl[p][q];
            float mx = -dk[0];
            #pragma unroll
            for (int q = 1; q < KK; ++q) mx = fmaxf(mx, -dk[q]);
            float wks[KK], sum = 0.f;
            #pragma unroll
            for (int q = 0; q < KK; ++q) { wks[q] = __expf(-dk[q] - mx); sum += wks[q]; }
            float inv = 1.0f / sum;
            float agg = 0.f;
            #pragma unroll
            for (int q = 0; q < KK; ++q) agg += wks[q] * inv * xtr[q][p][lane];

            float vv = (lane == 0) ? -agg * agg : agg * agg;
            #pragma unroll
            for (int m = 32; m > 0; m >>= 1) vv += __shfl_xor(vv, m);
            float den = sqrtf(fmaxf(fabsf(vv), 1e-8f));
            F[(size_t)(pbase + p) * DD + lane] = agg / den;
        }
        __syncthreads();  // xtr/disl reused next round
    }

    // ---- grid-wide barrier: F complete & visible across XCDs ----
    __threadfence();
    cg::this_grid().sync();

    // ---- pass B: this block's 48 n's (6 per wave) ----
    const float4* F4 = (const float4*)F;
    const int nbase = blk * PTSB;
    for (int i = 0; i < 6; ++i) {
        const int n = nbase + k * 6 + i;
        float4 acc = {0.f, 0.f, 0.f, 0.f};
        #pragma unroll
        for (int mq = 0; mq < 8; ++mq) {
            int   m   = mq * 4 + g;
            int   j   = nei[n * NNEI + m];
            float wgt = (float)mask[n * NNEI + m] + 1e-4f;
            float4 v  = F4[(size_t)j * 16 + c];
            acc.x += wgt * v.x; acc.y += wgt * v.y;
            acc.z += wgt * v.z; acc.w += wgt * v.w;
        }
        #pragma unroll
        for (int m = 16; m <= 32; m <<= 1) {
            acc.x += __shfl_xor(acc.x, m); acc.y += __shfl_xor(acc.y, m);
            acc.z += __shfl_xor(acc.z, m); acc.w += __shfl_xor(acc.w, m);
        }
        float s = acc.x * acc.x + acc.y * acc.y + acc.z * acc.z + acc.w * acc.w;
        if (c == 0) s -= 2.0f * acc.x * acc.x;
        #pragma unroll
        for (int m = 1; m <= 8; m <<= 1) s += __shfl_xor(s, m);
        float den = sqrtf(fmaxf(fabsf(s), 1e-8f));
        if (g == 0) {
            float4 rr = {acc.x / den, acc.y / den, acc.z / den, acc.w / den};
            ((float4*)out)[(size_t)n * 16 + c] = rr;
        }
    }
}

// ================= fallback path (3 kernels, proven round-3 code) =================
__global__ void prep_kernel(const float* __restrict__ kp,
                            const float* __restrict__ scales,
                            float* __restrict__ km,
                            float* __restrict__ escale) {
    int l = threadIdx.x;
    #pragma unroll
    for (int k = 0; k < KK; ++k) {
        float sp = (l == 0) ? 0.0f : kp[k * DD + l];
        float ss = sp * sp;
        #pragma unroll
        for (int off = 32; off > 0; off >>= 1) ss += __shfl_xor(ss, off);
        float nrm = sqrtf(fmaxf(ss, 1e-8f));
        float val = (l == 0) ? coshf(nrm) : -(sinhf(nrm) / nrm) * sp;
        km[k * DD + l] = val;
    }
    if (l < KK) escale[l] = expf(scales[l]);
}

__launch_bounds__(512)
__global__ void passA_kernel(const float* __restrict__ x,
                             const float* __restrict__ W,
                             const float* __restrict__ b,
                             const float* __restrict__ km,
                             const float* __restrict__ escale,
                             float* __restrict__ F) {
    __shared__ float xtr[KK][16][65];
    __shared__ float disl[16][12];
    const int t = threadIdx.x, k = t >> 6, lane = t & 63, c = lane & 15, g = lane >> 4;
    const int pbase = blockIdx.x * 16;
    bf16x8 Wh[4][2], Wl[4][2];
    #pragma unroll
    for (int nt = 0; nt < 4; ++nt)
        #pragma unroll
        for (int ks = 0; ks < 2; ++ks) {
            const float* wr = W + ((size_t)k * 64 + nt * 16 + c) * 64 + ks * 32 + g * 8;
            pack8(*(const float4*)wr, *(const float4*)(wr + 4), Wh[nt][ks], Wl[nt][ks]);
        }
    bf16x8 Mh[2], Ml[2];
    #pragma unroll
    for (int ks = 0; ks < 2; ++ks) {
        float4 u = {0,0,0,0}, v = {0,0,0,0};
        if (c < 8) {
            const float* mr = km + (size_t)c * 64 + ks * 32 + g * 8;
            u = *(const float4*)mr; v = *(const float4*)(mr + 4);
        }
        pack8(u, v, Mh[ks], Ml[ks]);
    }
    const float es = escale[k];
    float bnt[4];
    #pragma unroll
    for (int nt = 0; nt < 4; ++nt) bnt[nt] = b[k * 64 + nt * 16 + c];
    bf16x8 Ah[2], Al[2];
    {
        const float* xr = x + (size_t)(pbase + c) * 64 + g * 8;
        pack8(*(const float4*)(xr +  0), *(const float4*)(xr +  4), Ah[0], Al[0]);
        pack8(*(const float4*)(xr + 32), *(const float4*)(xr + 36), Ah[1], Al[1]);
    }
    f32x4 accY[4];
    #pragma unroll
    for (int nt = 0; nt < 4; ++nt) accY[nt] = (f32x4){0,0,0,0};
    f32x4 accI = (f32x4){0,0,0,0};
    #pragma unroll
    for (int ks = 0; ks < 2; ++ks) {
        #pragma unroll
        for (int nt = 0; nt < 4; ++nt) {
            accY[nt] = MFMA16(Ah[ks], Wh[nt][ks], accY[nt]);
            accY[nt] = MFMA16(Ah[ks], Wl[nt][ks], accY[nt]);
            accY[nt] = MFMA16(Al[ks], Wh[nt][ks], accY[nt]);
        }
        accI = MFMA16(Ah[ks], Mh[ks], accI);
        accI = MFMA16(Ah[ks], Ml[ks], accI);
        accI = MFMA16(Al[ks], Mh[ks], accI);
    }
    float yv[4][4], sall[4];
    #pragma unroll
    for (int rr = 0; rr < 4; ++rr) {
        float s = 0.f;
        #pragma unroll
        for (int nt = 0; nt < 4; ++nt) { float y = accY[nt][rr] + bnt[nt]; yv[nt][rr] = y; s += y * y; }
        sall[rr] = s;
    }
    #pragma unroll
    for (int m = 1; m <= 8; m <<= 1)
        #pragma unroll
        for (int rr = 0; rr < 4; ++rr) sall[rr] += __shfl_xor(sall[rr], m);
    float y0[4];
    #pragma unroll
    for (int rr = 0; rr < 4; ++rr) y0[rr] = __shfl(yv[0][rr], lane & 48);
    #pragma unroll
    for (int rr = 0; rr < 4; ++rr) {
        const int p = g * 4 + rr;
        float nar2 = fmaxf(sall[rr] - y0[rr] * y0[rr], 1e-8f);
        float time = es / (1.0f + expf(-y0[rr])) + 1.0001f;
        float s3   = sqrtf((time * time - 1.0f) / nar2);
        #pragma unroll
        for (int nt = 0; nt < 4; ++nt) {
            float v = yv[nt][rr] * s3;
            if (nt == 0 && c == 0) v = time;
            xtr[k][p][nt * 16 + c] = v;
        }
    }
    if (k == 0) {
        #pragma unroll
        for (int rr = 0; rr < 4; ++rr) {
            float nc = fmaxf(accI[rr], 1.0f + 1e-7f);
            float dis = logf(nc + sqrtf(nc * nc - 1.0f));
            if (c < 8) disl[g * 4 + rr][c] = dis;
        }
    }
    __syncthreads();
    #pragma unroll
    for (int pi = 0; pi < 2; ++pi) {
        const int p = k * 2 + pi;
        float dk[KK];
        #pragma unroll
        for (int q = 0; q < KK; ++q) dk[q] = disl[p][q];
        float mx = -dk[0];
        #pragma unroll
        for (int q = 1; q < KK; ++q) mx = fmaxf(mx, -dk[q]);
        float wks[KK], sum = 0.f;
        #pragma unroll
        for (int q = 0; q < KK; ++q) { wks[q] = expf(-dk[q] - mx); sum += wks[q]; }
        float inv = 1.0f / sum;
        float agg = 0.f;
        #pragma unroll
        for (int q = 0; q < KK; ++q) agg += wks[q] * inv * xtr[q][p][lane];
        float vv = (lane == 0) ? -agg * agg : agg * agg;
        #pragma unroll
        for (int m = 32; m > 0; m >>= 1) vv += __shfl_xor(vv, m);
        float den = sqrtf(fmaxf(fabsf(vv), 1e-8f));
        F[(size_t)(pbase + p) * DD + lane] = agg / den;
    }
}

__launch_bounds__(256)
__global__ void passB_kernel(const float* __restrict__ F,
                             const int* __restrict__ nei,
                             const int* __restrict__ mask,
                             float* __restrict__ out) {
    const int t = threadIdx.x, wave = t >> 6, lane = t & 63, c = lane & 15, g = lane >> 4;
    const int n = blockIdx.x * 4 + wave;
    const float4* F4 = (const float4*)F;
    float4 acc = {0,0,0,0};
    #pragma unroll
    for (int mq = 0; mq < 8; ++mq) {
        int m = mq * 4 + g;
        int j = nei[n * NNEI + m];
        float wgt = (float)mask[n * NNEI + m] + 1e-4f;
        float4 v = F4[(size_t)j * 16 + c];
        acc.x += wgt * v.x; acc.y += wgt * v.y; acc.z += wgt * v.z; acc.w += wgt * v.w;
    }
    #pragma unroll
    for (int m = 16; m <= 32; m <<= 1) {
        acc.x += __shfl_xor(acc.x, m); acc.y += __shfl_xor(acc.y, m);
        acc.z += __shfl_xor(acc.z, m); acc.w += __shfl_xor(acc.w, m);
    }
    float s = acc.x * acc.x + acc.y * acc.y + acc.z * acc.z + acc.w * acc.w;
    if (c == 0) s -= 2.0f * acc.x * acc.x;
    #pragma unroll
    for (int m = 1; m <= 8; m <<= 1) s += __shfl_xor(s, m);
    float den = sqrtf(fmaxf(fabsf(s), 1e-8f));
    if (g == 0) {
        float4 rr = {acc.x / den, acc.y / den, acc.z / den, acc.w / den};
        ((float4*)out)[(size_t)n * 16 + c] = rr;
    }
}

// ---------------------------------------------------------------- launch ---
extern "C" void kernel_launch(void* const* d_in, const int* in_sizes, int n_in,
                              void* d_out, int out_size, void* d_ws, size_t ws_size,
                              hipStream_t stream) {
    const float* x      = (const float*)d_in[0];
    const int*   nei    = (const int*)  d_in[1];
    const int*   mask   = (const int*)  d_in[2];
    const float* kp     = (const float*)d_in[3];
    const float* W      = (const float*)d_in[4];
    const float* b      = (const float*)d_in[5];
    const float* scales = (const float*)d_in[6];
    float*       out    = (float*)d_out;

    // ws: [0, N*D) F ; then km (512) ; escale (8)  (fallback only uses km/escale)
    const size_t needed = (size_t)(NPTS * DD + 1024) * sizeof(float);
    if (ws_size < needed) return;
    float* F      = (float*)d_ws;
    float* km     = F + (size_t)NPTS * DD;
    float* escale = km + 512;

    void* args[9] = {(void*)&x, (void*)&nei, (void*)&mask, (void*)&kp, (void*)&W,
                     (void*)&b, (void*)&scales, (void*)&F, (void*)&out};
    hipError_t err = hipLaunchCooperativeKernel((const void*)fused_kernel,
                                                dim3(NBLK), dim3(512),
                                                (void**)args, 0, stream);
    if (err != hipSuccess) {
        // deterministic fallback: proven 3-kernel path
        prep_kernel<<<1, 64, 0, stream>>>(kp, scales, km, escale);
        passA_kernel<<<NPTS / 16, 512, 0, stream>>>(x, W, b, km, escale, F);
        passB_kernel<<<NPTS / 4, 256, 0, stream>>>(F, nei, mask, out);
    }
}

// Round 5
// 41.185 us; speedup vs baseline: 2.3569x; 2.3569x over previous
//
#include <hip/hip_runtime.h>
#include <math.h>

// Problem constants: N=12000, NEI=32, K=8, D=64
#define NPTS 12000
#define NNEI 32
#define KK   8
#define DD   64

// Structure (round 5): two kernels, both high-occupancy.
//   passA: 750 blocks x 512 thr (16 points/block, wave k = kernel k).
//          Inline prep (km via LDS, escale) -- no prep launch.
//          Split-bf16 MFMA: Y = X W^T (hh+hl+lh, fp32 acc, rel err ~2^-18),
//          plus an inner-product MFMA tile giving dis for all 8 k at once.
//   passB: 3000 blocks x 256 thr (wave per n). nei/mask fetched as ONE
//          coalesced 256B load per wave (lanes 0..31 nei, 32..63 mask),
//          distributed via __shfl; F rows gathered as float4.

typedef __bf16 bf16x8 __attribute__((ext_vector_type(8)));
typedef float  f32x4  __attribute__((ext_vector_type(4)));

#define MFMA16(A, B, C) __builtin_amdgcn_mfma_f32_16x16x32_bf16((A), (B), (C), 0, 0, 0)

__device__ __forceinline__ void pack8(float4 u, float4 v, bf16x8& h, bf16x8& l) {
    float a[8] = {u.x, u.y, u.z, u.w, v.x, v.y, v.z, v.w};
    #pragma unroll
    for (int i = 0; i < 8; ++i) {
        __bf16 hh = (__bf16)a[i];
        h[i] = hh;
        l[i] = (__bf16)(a[i] - (float)hh);
    }
}

// ---------------------------------------------------------------- pass A ---
__launch_bounds__(512)
__global__ void passA_kernel(const float* __restrict__ x,
                             const float* __restrict__ kp,
                             const float* __restrict__ W,
                             const float* __restrict__ b,
                             const float* __restrict__ scales,
                             float* __restrict__ F) {
    __shared__ float xtr[KK][16][65];   // pad 65 -> conflict-free combine reads
    __shared__ float kmL[KK][DD];
    __shared__ float disl[16][12];

    const int t    = threadIdx.x;
    const int k    = t >> 6;            // wave index == kernel index
    const int lane = t & 63;
    const int c    = lane & 15;
    const int g    = lane >> 4;
    const int pbase = blockIdx.x * 16;

    // ---- inline prep: km row for this wave's k (kernels*metric) ----
    {
        float spv = (lane == 0) ? 0.f : kp[k * DD + lane];   // kp[:,0]==0
        float ss = spv * spv;
        #pragma unroll
        for (int off = 32; off > 0; off >>= 1) ss += __shfl_xor(ss, off);
        float nrm = sqrtf(fmaxf(ss, 1e-8f));
        float e  = __expf(nrm);
        float ei = 1.0f / e;
        float ch = 0.5f * (e + ei);
        float sh = 0.5f * (e - ei);
        kmL[k][lane] = (lane == 0) ? ch : -(sh / nrm) * spv;
    }
    const float es = __expf(scales[k]);

    // ---- W_k fragments (hi/lo) ----
    bf16x8 Wh[4][2], Wl[4][2];
    #pragma unroll
    for (int nt = 0; nt < 4; ++nt)
        #pragma unroll
        for (int ks = 0; ks < 2; ++ks) {
            const float* wr = W + ((size_t)k * DD + nt * 16 + c) * DD + ks * 32 + g * 8;
            pack8(*(const float4*)wr, *(const float4*)(wr + 4), Wh[nt][ks], Wl[nt][ks]);
        }
    float bnt[4];
    #pragma unroll
    for (int nt = 0; nt < 4; ++nt) bnt[nt] = b[k * DD + nt * 16 + c];

    // ---- A fragments: this block's 16 x-rows ----
    bf16x8 Ah[2], Al[2];
    {
        const float* xr = x + (size_t)(pbase + c) * DD + g * 8;
        pack8(*(const float4*)(xr +  0), *(const float4*)(xr +  4), Ah[0], Al[0]);
        pack8(*(const float4*)(xr + 32), *(const float4*)(xr + 36), Ah[1], Al[1]);
    }

    __syncthreads();  // kmL ready

    // km fragments from LDS (rows 8..15 zero)
    bf16x8 Mh[2], Ml[2];
    #pragma unroll
    for (int ks = 0; ks < 2; ++ks)
        #pragma unroll
        for (int j = 0; j < 8; ++j) {
            float v = (c < 8) ? kmL[c][ks * 32 + g * 8 + j] : 0.f;
            __bf16 hh = (__bf16)v;
            Mh[ks][j] = hh;
            Ml[ks][j] = (__bf16)(v - (float)hh);
        }

    // ---- MFMAs ----
    f32x4 accY[4];
    #pragma unroll
    for (int nt = 0; nt < 4; ++nt) accY[nt] = (f32x4){0.f, 0.f, 0.f, 0.f};
    f32x4 accI = (f32x4){0.f, 0.f, 0.f, 0.f};
    #pragma unroll
    for (int ks = 0; ks < 2; ++ks) {
        #pragma unroll
        for (int nt = 0; nt < 4; ++nt) {
            accY[nt] = MFMA16(Ah[ks], Wh[nt][ks], accY[nt]);
            accY[nt] = MFMA16(Ah[ks], Wl[nt][ks], accY[nt]);
            accY[nt] = MFMA16(Al[ks], Wh[nt][ks], accY[nt]);
        }
        accI = MFMA16(Ah[ks], Mh[ks], accI);
        accI = MFMA16(Ah[ks], Ml[ks], accI);
        accI = MFMA16(Al[ks], Mh[ks], accI);
    }

    // ---- epilogue: per-point stats (C layout: row p=g*4+rr, col o=nt*16+c) ----
    float yv[4][4], sall[4];
    #pragma unroll
    for (int rr = 0; rr < 4; ++rr) {
        float s = 0.f;
        #pragma unroll
        for (int nt = 0; nt < 4; ++nt) {
            float y = accY[nt][rr] + bnt[nt];
            yv[nt][rr] = y;
            s += y * y;
        }
        sall[rr] = s;
    }
    #pragma unroll
    for (int m = 1; m <= 8; m <<= 1)
        #pragma unroll
        for (int rr = 0; rr < 4; ++rr) sall[rr] += __shfl_xor(sall[rr], m);
    float y0[4];
    #pragma unroll
    for (int rr = 0; rr < 4; ++rr) y0[rr] = __shfl(yv[0][rr], lane & 48);

    #pragma unroll
    for (int rr = 0; rr < 4; ++rr) {
        const int p = g * 4 + rr;
        float nar2 = fmaxf(sall[rr] - y0[rr] * y0[rr], 1e-8f);
        float time = es / (1.0f + __expf(-y0[rr])) + 1.0001f;
        float s3   = sqrtf((time * time - 1.0f) / nar2);
        #pragma unroll
        for (int nt = 0; nt < 4; ++nt) {
            float v = yv[nt][rr] * s3;
            if (nt == 0 && c == 0) v = time;
            xtr[k][p][nt * 16 + c] = v;
        }
    }
    if (k == 0) {
        #pragma unroll
        for (int rr = 0; rr < 4; ++rr) {
            float nc  = fmaxf(accI[rr], 1.0f + 1e-7f);
            float dis = __logf(nc + sqrtf(nc * nc - 1.0f));  // arccosh
            if (c < 8) disl[g * 4 + rr][c] = dis;
        }
    }
    __syncthreads();

    // ---- combine: wave k handles points {2k, 2k+1} ----
    #pragma unroll
    for (int pi = 0; pi < 2; ++pi) {
        const int p = k * 2 + pi;
        float dk[KK];
        #pragma unroll
        for (int q = 0; q < KK; ++q) dk[q] = disl[p][q];
        float mx = -dk[0];
        #pragma unroll
        for (int q = 1; q < KK; ++q) mx = fmaxf(mx, -dk[q]);
        float wks[KK], sum = 0.f;
        #pragma unroll
        for (int q = 0; q < KK; ++q) { wks[q] = __expf(-dk[q] - mx); sum += wks[q]; }
        float inv = 1.0f / sum;
        float agg = 0.f;
        #pragma unroll
        for (int q = 0; q < KK; ++q) agg += wks[q] * inv * xtr[q][p][lane];

        float vv = (lane == 0) ? -agg * agg : agg * agg;
        #pragma unroll
        for (int m = 32; m > 0; m >>= 1) vv += __shfl_xor(vv, m);
        float den = sqrtf(fmaxf(fabsf(vv), 1e-8f));
        F[(size_t)(pbase + p) * DD + lane] = agg / den;
    }
}

// ---------------------------------------------------------------- pass B ---
__launch_bounds__(256)
__global__ void passB_kernel(const float* __restrict__ F,
                             const int* __restrict__ nei,
                             const int* __restrict__ mask,
                             float* __restrict__ out) {
    const int t    = threadIdx.x;
    const int wave = t >> 6;
    const int lane = t & 63;
    const int c    = lane & 15;   // col quad: o = 4c..4c+3
    const int g    = lane >> 4;   // m sub-index
    const int n    = blockIdx.x * 4 + wave;

    // one coalesced 256B fetch per wave: lanes 0..31 nei row, 32..63 mask row
    int vsrc;
    if (lane < 32) vsrc = nei[n * NNEI + lane];
    else           vsrc = mask[n * NNEI + (lane - 32)];

    const float4* F4 = (const float4*)F;
    float4 acc = {0.f, 0.f, 0.f, 0.f};
    #pragma unroll
    for (int mq = 0; mq < 8; ++mq) {
        int   m   = mq * 4 + g;
        int   j   = __shfl(vsrc, m);
        float wgt = (float)__shfl(vsrc, 32 + m) + 1e-4f;
        float4 v  = F4[(size_t)j * 16 + c];
        acc.x += wgt * v.x; acc.y += wgt * v.y;
        acc.z += wgt * v.z; acc.w += wgt * v.w;
    }
    // reduce over the 4 m-subgroups (lanes xor 16, 32)
    #pragma unroll
    for (int m = 16; m <= 32; m <<= 1) {
        acc.x += __shfl_xor(acc.x, m); acc.y += __shfl_xor(acc.y, m);
        acc.z += __shfl_xor(acc.z, m); acc.w += __shfl_xor(acc.w, m);
    }
    // lorentz inner: minus sign on o==0 (lane c==0, component .x)
    float s = acc.x * acc.x + acc.y * acc.y + acc.z * acc.z + acc.w * acc.w;
    if (c == 0) s -= 2.0f * acc.x * acc.x;
    #pragma unroll
    for (int m = 1; m <= 8; m <<= 1) s += __shfl_xor(s, m);
    float den = sqrtf(fmaxf(fabsf(s), 1e-8f));
    if (g == 0) {
        float4 rr = {acc.x / den, acc.y / den, acc.z / den, acc.w / den};
        ((float4*)out)[(size_t)n * 16 + c] = rr;
    }
}

// ---------------------------------------------------------------- launch ---
extern "C" void kernel_launch(void* const* d_in, const int* in_sizes, int n_in,
                              void* d_out, int out_size, void* d_ws, size_t ws_size,
                              hipStream_t stream) {
    const float* x      = (const float*)d_in[0];  // (12000, 64) f32
    const int*   nei    = (const int*)  d_in[1];  // (12000, 32) int32
    const int*   mask   = (const int*)  d_in[2];  // (12000, 32) int32
    const float* kp     = (const float*)d_in[3];  // (8, 64) f32
    const float* W      = (const float*)d_in[4];  // (8, 64, 64) f32
    const float* b      = (const float*)d_in[5];  // (8, 64) f32
    const float* scales = (const float*)d_in[6];  // (8,) f32
    float*       out    = (float*)d_out;          // (12000, 64) f32

    const size_t needed = (size_t)(NPTS * DD) * sizeof(float);
    if (ws_size < needed) return;
    float* F = (float*)d_ws;

    passA_kernel<<<NPTS / 16, 512, 0, stream>>>(x, kp, W, b, scales, F);
    passB_kernel<<<NPTS / 4, 256, 0, stream>>>(F, nei, mask, out);
}

// Round 6
// 34.126 us; speedup vs baseline: 2.8444x; 1.2068x over previous
//
#include <hip/hip_runtime.h>
#include <math.h>

// Problem constants: N=12000, NEI=32, K=8, D=64
#define NPTS 12000
#define NNEI 32
#define KK   8
#define DD   64

// Round 6: W fragments pre-packed to bf16 hi/lo in fragment order (packW
// kernel, runs once per call). passA's W read becomes 8 coalesced b128 loads
// per lane (was: 16 dwordx4 at 256B stride = 64x 16B L2 requests/instr, the
// round-5 bottleneck theory). Rest unchanged from round 5.

typedef __bf16 bf16x8 __attribute__((ext_vector_type(8)));
typedef float  f32x4  __attribute__((ext_vector_type(4)));

#define MFMA16(A, B, C) __builtin_amdgcn_mfma_f32_16x16x32_bf16((A), (B), (C), 0, 0, 0)

__device__ __forceinline__ void pack8(float4 u, float4 v, bf16x8& h, bf16x8& l) {
    float a[8] = {u.x, u.y, u.z, u.w, v.x, v.y, v.z, v.w};
    #pragma unroll
    for (int i = 0; i < 8; ++i) {
        __bf16 hh = (__bf16)a[i];
        h[i] = hh;
        l[i] = (__bf16)(a[i] - (float)hh);
    }
}

// ---------------------------------------------------------------- packW ----
// One thread per (k, nt, ks, lane): 8*4*2*64 = 4096 threads.
// Wpk[(((k*4+nt)*2+ks)*2+h)*64 + lane] = bf16x8 fragment (h=0 hi, h=1 lo).
__launch_bounds__(512)
__global__ void packW_kernel(const float* __restrict__ W,
                             bf16x8* __restrict__ Wpk) {
    const int id   = blockIdx.x * 512 + threadIdx.x;   // 0..4095
    const int lane = id & 63;
    const int ks   = (id >> 6) & 1;
    const int nt   = (id >> 7) & 3;
    const int k    = id >> 9;
    const int c    = lane & 15;
    const int g    = lane >> 4;

    const float* wr = W + ((size_t)k * DD + nt * 16 + c) * DD + ks * 32 + g * 8;
    bf16x8 h, l;
    pack8(*(const float4*)wr, *(const float4*)(wr + 4), h, l);
    const size_t base = ((((size_t)k * 4 + nt) * 2 + ks) * 2) * 64 + lane;
    Wpk[base]      = h;   // hi plane
    Wpk[base + 64] = l;   // lo plane
}

// ---------------------------------------------------------------- pass A ---
__launch_bounds__(512)
__global__ void passA_kernel(const float* __restrict__ x,
                             const float* __restrict__ kp,
                             const bf16x8* __restrict__ Wpk,
                             const float* __restrict__ b,
                             const float* __restrict__ scales,
                             float* __restrict__ F) {
    __shared__ float xtr[KK][16][65];   // pad 65 -> conflict-free combine reads
    __shared__ float kmL[KK][DD];
    __shared__ float disl[16][12];

    const int t    = threadIdx.x;
    const int k    = t >> 6;            // wave index == kernel index
    const int lane = t & 63;
    const int c    = lane & 15;
    const int g    = lane >> 4;
    const int pbase = blockIdx.x * 16;

    // ---- inline prep: km row for this wave's k (kernels*metric) ----
    {
        float spv = (lane == 0) ? 0.f : kp[k * DD + lane];   // kp[:,0]==0
        float ss = spv * spv;
        #pragma unroll
        for (int off = 32; off > 0; off >>= 1) ss += __shfl_xor(ss, off);
        float nrm = sqrtf(fmaxf(ss, 1e-8f));
        float e  = __expf(nrm);
        float ei = 1.0f / e;
        float ch = 0.5f * (e + ei);
        float sh = 0.5f * (e - ei);
        kmL[k][lane] = (lane == 0) ? ch : -(sh / nrm) * spv;
    }
    const float es = __expf(scales[k]);

    // ---- W_k fragments: coalesced b128 loads from pre-packed buffer ----
    bf16x8 Wh[4][2], Wl[4][2];
    #pragma unroll
    for (int nt = 0; nt < 4; ++nt)
        #pragma unroll
        for (int ks = 0; ks < 2; ++ks) {
            const size_t base = ((((size_t)k * 4 + nt) * 2 + ks) * 2) * 64 + lane;
            Wh[nt][ks] = Wpk[base];
            Wl[nt][ks] = Wpk[base + 64];
        }
    float bnt[4];
    #pragma unroll
    for (int nt = 0; nt < 4; ++nt) bnt[nt] = b[k * DD + nt * 16 + c];

    // ---- A fragments: this block's 16 x-rows ----
    bf16x8 Ah[2], Al[2];
    {
        const float* xr = x + (size_t)(pbase + c) * DD + g * 8;
        pack8(*(const float4*)(xr +  0), *(const float4*)(xr +  4), Ah[0], Al[0]);
        pack8(*(const float4*)(xr + 32), *(const float4*)(xr + 36), Ah[1], Al[1]);
    }

    __syncthreads();  // kmL ready

    // km fragments from LDS (rows 8..15 zero)
    bf16x8 Mh[2], Ml[2];
    #pragma unroll
    for (int ks = 0; ks < 2; ++ks)
        #pragma unroll
        for (int j = 0; j < 8; ++j) {
            float v = (c < 8) ? kmL[c][ks * 32 + g * 8 + j] : 0.f;
            __bf16 hh = (__bf16)v;
            Mh[ks][j] = hh;
            Ml[ks][j] = (__bf16)(v - (float)hh);
        }

    // ---- MFMAs ----
    f32x4 accY[4];
    #pragma unroll
    for (int nt = 0; nt < 4; ++nt) accY[nt] = (f32x4){0.f, 0.f, 0.f, 0.f};
    f32x4 accI = (f32x4){0.f, 0.f, 0.f, 0.f};
    #pragma unroll
    for (int ks = 0; ks < 2; ++ks) {
        #pragma unroll
        for (int nt = 0; nt < 4; ++nt) {
            accY[nt] = MFMA16(Ah[ks], Wh[nt][ks], accY[nt]);
            accY[nt] = MFMA16(Ah[ks], Wl[nt][ks], accY[nt]);
            accY[nt] = MFMA16(Al[ks], Wh[nt][ks], accY[nt]);
        }
        accI = MFMA16(Ah[ks], Mh[ks], accI);
        accI = MFMA16(Ah[ks], Ml[ks], accI);
        accI = MFMA16(Al[ks], Mh[ks], accI);
    }

    // ---- epilogue: per-point stats (C layout: row p=g*4+rr, col o=nt*16+c) ----
    float yv[4][4], sall[4];
    #pragma unroll
    for (int rr = 0; rr < 4; ++rr) {
        float s = 0.f;
        #pragma unroll
        for (int nt = 0; nt < 4; ++nt) {
            float y = accY[nt][rr] + bnt[nt];
            yv[nt][rr] = y;
            s += y * y;
        }
        sall[rr] = s;
    }
    #pragma unroll
    for (int m = 1; m <= 8; m <<= 1)
        #pragma unroll
        for (int rr = 0; rr < 4; ++rr) sall[rr] += __shfl_xor(sall[rr], m);
    float y0[4];
    #pragma unroll
    for (int rr = 0; rr < 4; ++rr) y0[rr] = __shfl(yv[0][rr], lane & 48);

    #pragma unroll
    for (int rr = 0; rr < 4; ++rr) {
        const int p = g * 4 + rr;
        float nar2 = fmaxf(sall[rr] - y0[rr] * y0[rr], 1e-8f);
        float time = es / (1.0f + __expf(-y0[rr])) + 1.0001f;
        float s3   = sqrtf((time * time - 1.0f) / nar2);
        #pragma unroll
        for (int nt = 0; nt < 4; ++nt) {
            float v = yv[nt][rr] * s3;
            if (nt == 0 && c == 0) v = time;
            xtr[k][p][nt * 16 + c] = v;
        }
    }
    if (k == 0) {
        #pragma unroll
        for (int rr = 0; rr < 4; ++rr) {
            float nc  = fmaxf(accI[rr], 1.0f + 1e-7f);
            float dis = __logf(nc + sqrtf(nc * nc - 1.0f));  // arccosh
            if (c < 8) disl[g * 4 + rr][c] = dis;
        }
    }
    __syncthreads();

    // ---- combine: wave k handles points {2k, 2k+1} ----
    #pragma unroll
    for (int pi = 0; pi < 2; ++pi) {
        const int p = k * 2 + pi;
        float dk[KK];
        #pragma unroll
        for (int q = 0; q < KK; ++q) dk[q] = disl[p][q];
        float mx = -dk[0];
        #pragma unroll
        for (int q = 1; q < KK; ++q) mx = fmaxf(mx, -dk[q]);
        float wks[KK], sum = 0.f;
        #pragma unroll
        for (int q = 0; q < KK; ++q) { wks[q] = __expf(-dk[q] - mx); sum += wks[q]; }
        float inv = 1.0f / sum;
        float agg = 0.f;
        #pragma unroll
        for (int q = 0; q < KK; ++q) agg += wks[q] * inv * xtr[q][p][lane];

        float vv = (lane == 0) ? -agg * agg : agg * agg;
        #pragma unroll
        for (int m = 32; m > 0; m >>= 1) vv += __shfl_xor(vv, m);
        float den = sqrtf(fmaxf(fabsf(vv), 1e-8f));
        F[(size_t)(pbase + p) * DD + lane] = agg / den;
    }
}

// ---------------------------------------------------------------- pass B ---
__launch_bounds__(256)
__global__ void passB_kernel(const float* __restrict__ F,
                             const int* __restrict__ nei,
                             const int* __restrict__ mask,
                             float* __restrict__ out) {
    const int t    = threadIdx.x;
    const int wave = t >> 6;
    const int lane = t & 63;
    const int c    = lane & 15;   // col quad: o = 4c..4c+3
    const int g    = lane >> 4;   // m sub-index
    const int n    = blockIdx.x * 4 + wave;

    // one coalesced 256B fetch per wave: lanes 0..31 nei row, 32..63 mask row
    int vsrc;
    if (lane < 32) vsrc = nei[n * NNEI + lane];
    else           vsrc = mask[n * NNEI + (lane - 32)];

    const float4* F4 = (const float4*)F;
    float4 acc = {0.f, 0.f, 0.f, 0.f};
    #pragma unroll
    for (int mq = 0; mq < 8; ++mq) {
        int   m   = mq * 4 + g;
        int   j   = __shfl(vsrc, m);
        float wgt = (float)__shfl(vsrc, 32 + m) + 1e-4f;
        float4 v  = F4[(size_t)j * 16 + c];
        acc.x += wgt * v.x; acc.y += wgt * v.y;
        acc.z += wgt * v.z; acc.w += wgt * v.w;
    }
    // reduce over the 4 m-subgroups (lanes xor 16, 32)
    #pragma unroll
    for (int m = 16; m <= 32; m <<= 1) {
        acc.x += __shfl_xor(acc.x, m); acc.y += __shfl_xor(acc.y, m);
        acc.z += __shfl_xor(acc.z, m); acc.w += __shfl_xor(acc.w, m);
    }
    // lorentz inner: minus sign on o==0 (lane c==0, component .x)
    float s = acc.x * acc.x + acc.y * acc.y + acc.z * acc.z + acc.w * acc.w;
    if (c == 0) s -= 2.0f * acc.x * acc.x;
    #pragma unroll
    for (int m = 1; m <= 8; m <<= 1) s += __shfl_xor(s, m);
    float den = sqrtf(fmaxf(fabsf(s), 1e-8f));
    if (g == 0) {
        float4 rr = {acc.x / den, acc.y / den, acc.z / den, acc.w / den};
        ((float4*)out)[(size_t)n * 16 + c] = rr;
    }
}

// ---------------------------------------------------------------- launch ---
extern "C" void kernel_launch(void* const* d_in, const int* in_sizes, int n_in,
                              void* d_out, int out_size, void* d_ws, size_t ws_size,
                              hipStream_t stream) {
    const float* x      = (const float*)d_in[0];  // (12000, 64) f32
    const int*   nei    = (const int*)  d_in[1];  // (12000, 32) int32
    const int*   mask   = (const int*)  d_in[2];  // (12000, 32) int32
    const float* kp     = (const float*)d_in[3];  // (8, 64) f32
    const float* W      = (const float*)d_in[4];  // (8, 64, 64) f32
    const float* b      = (const float*)d_in[5];  // (8, 64) f32
    const float* scales = (const float*)d_in[6];  // (8,) f32
    float*       out    = (float*)d_out;          // (12000, 64) f32

    // ws: [0, N*D) F (f32) ; then Wpk: 8192 bf16x8 entries (128 KB, 16B-aligned)
    const size_t needed = (size_t)(NPTS * DD) * sizeof(float) + 8192 * 16;
    if (ws_size < needed) return;
    float*  F   = (float*)d_ws;
    bf16x8* Wpk = (bf16x8*)(F + (size_t)NPTS * DD);

    packW_kernel<<<8, 512, 0, stream>>>(W, Wpk);
    passA_kernel<<<NPTS / 16, 512, 0, stream>>>(x, kp, Wpk, b, scales, F);
    passB_kernel<<<NPTS / 4, 256, 0, stream>>>(F, nei, mask, out);
}